// Round 1
// 244.926 us; speedup vs baseline: 1.0705x; 1.0705x over previous
//
#include <hip/hip_runtime.h>

#define NT 256
#define TILE 256      // nodes per bucket
#define TILE_SH 8
#define BSTRIDE 8192  // padded edge slots per bucket (mean 4096, sigma 64)
#define BSTRIDE_SH 13
#define EPB 4096      // edges per block in bucket scatter pass
#define ITB 16        // EPB / NT
#define NBUCK_PAD 512

static inline int cdiv(long long a, long long b) { return (int)((a + b - 1) / b); }

typedef unsigned int uint32;
typedef unsigned short ushort16;
typedef short bf16x8 __attribute__((ext_vector_type(8)));
typedef float f32x4 __attribute__((ext_vector_type(4)));

__device__ __forceinline__ ushort16 f2bf(float f) {
  uint32 u = __float_as_uint(f);
  u = (u + 0x7FFF + ((u >> 16) & 1)) >> 16;  // round-to-nearest-even
  return (ushort16)u;
}
__device__ __forceinline__ float bflo(uint32 w) { return __uint_as_float(w << 16); }
__device__ __forceinline__ float bfhi(uint32 w) { return __uint_as_float(w & 0xFFFF0000u); }
__device__ __forceinline__ float bf2f(ushort16 h) { return __uint_as_float(((uint32)h) << 16); }

// MFMA GEMM body: Yb[v,0:64] = bf16(X[v,0:K] @ W[K,64])   (NO dinv here anymore --
// dinv is applied per-edge in the gather so this kernel has no CSR dependency).
// Block = 64 nodes, 4 waves; wave w owns rows w*16..w*16+16.
// D = mfma(W_frag, X_frag): C/D col (lane&15) = node, row (quad*4+reg) = out-dim.
// SPLIT: X fp32 -> hi+lo bf16, 2 chained MFMAs (error = W rounding only).
// BFIN: X already bf16-packed rows (exact A operand).
template <int K, int BFIN, int SPLIT>
__device__ __forceinline__ void gemm_body(const void* __restrict__ Xp,
                                          const float* __restrict__ W,
                                          uint2* __restrict__ Yb, int n, int base,
                                          unsigned short* Xh, unsigned short* XlA,
                                          unsigned short* Wt) {
  constexpr int STR = K + 8;  // row stride (bf16 elems): +8 keeps b128 reads 2-way-only
  const int tid = threadIdx.x;

  // stage W (fp32 [k][64]) -> bf16 transposed Wt[n][k]
  for (int i = tid; i < K * 64; i += NT) {
    int k = i >> 6, nn = i & 63;
    Wt[nn * STR + k] = f2bf(W[i]);
  }
  if (BFIN) {  // bf16 rows: K/8 uint4 per row
    constexpr int NU = K / 8;
    const uint4* X4 = (const uint4*)Xp;
    for (int i = tid; i < 64 * NU; i += NT) {
      int row = i / NU, u = i % NU;
      int v = base + row;
      uint4 val = make_uint4(0u, 0u, 0u, 0u);
      if (v < n) val = X4[(size_t)v * NU + u];
      *(uint4*)&Xh[row * STR + u * 8] = val;
    }
  } else {  // fp32 rows -> hi (+lo) bf16
    constexpr int KQ = K / 4;
    const float4* X4 = (const float4*)Xp;
    for (int i = tid; i < 64 * KQ; i += NT) {
      int row = i / KQ, q = i % KQ;
      int v = base + row;
      float4 val = make_float4(0.f, 0.f, 0.f, 0.f);
      if (v < n) val = X4[(size_t)v * KQ + q];
      ushort16 h0 = f2bf(val.x), h1 = f2bf(val.y), h2 = f2bf(val.z), h3 = f2bf(val.w);
      uint2 hh;
      hh.x = (uint32)h0 | ((uint32)h1 << 16);
      hh.y = (uint32)h2 | ((uint32)h3 << 16);
      *(uint2*)&Xh[row * STR + q * 4] = hh;
      if (SPLIT) {
        ushort16 l0 = f2bf(val.x - bf2f(h0)), l1 = f2bf(val.y - bf2f(h1));
        ushort16 l2 = f2bf(val.z - bf2f(h2)), l3 = f2bf(val.w - bf2f(h3));
        uint2 ll;
        ll.x = (uint32)l0 | ((uint32)l1 << 16);
        ll.y = (uint32)l2 | ((uint32)l3 << 16);
        *(uint2*)&XlA[row * STR + q * 4] = ll;
      }
    }
  }
  __syncthreads();

  const int w = tid >> 6;
  const int lane = tid & 63;
  const int r = lane & 15;
  const int quad = lane >> 4;
  const int rloc = w * 16 + r;  // node row within tile (this lane's node)

  f32x4 acc[4];
#pragma unroll
  for (int i = 0; i < 4; ++i) acc[i] = (f32x4)(0.f);

#pragma unroll
  for (int ks = 0; ks < K / 32; ++ks) {
    const int koff = ks * 32 + quad * 8;
    bf16x8 xh = *(const bf16x8*)&Xh[rloc * STR + koff];
    bf16x8 xl;
    if (SPLIT) xl = *(const bf16x8*)&XlA[rloc * STR + koff];
#pragma unroll
    for (int nt = 0; nt < 4; ++nt) {
      bf16x8 wf = *(const bf16x8*)&Wt[(nt * 16 + r) * STR + koff];
      if (SPLIT)
        acc[nt] = __builtin_amdgcn_mfma_f32_16x16x32_bf16(wf, xl, acc[nt], 0, 0, 0);
      acc[nt] = __builtin_amdgcn_mfma_f32_16x16x32_bf16(wf, xh, acc[nt], 0, 0, 0);
    }
  }

  int v = base + rloc;
  if (v < n) {
#pragma unroll
    for (int nt = 0; nt < 4; ++nt) {
      // reg i holds out-dim n = nt*16 + quad*4 + i for node v
      uint2 u;
      u.x = (uint32)f2bf(acc[nt][0]) | ((uint32)f2bf(acc[nt][1]) << 16);
      u.y = (uint32)f2bf(acc[nt][2]) | ((uint32)f2bf(acc[nt][3]) << 16);
      Yb[(size_t)v * 16 + nt * 4 + quad] = u;
    }
  }
}

struct GemmSh {
  unsigned short Xh[64 * 136];
  unsigned short Xl[64 * 136];
  unsigned short Wt[64 * 136];
};
struct ScatSh {
  int cnt[NBUCK_PAD];
  int lcur[NBUCK_PAD];
  int delta[NBUCK_PAD];
  int hs[NT];
  uint32 sorted[EPB];
  unsigned short bid[EPB];
};
union FusedSh {
  GemmSh g;
  ScatSh s;
};

// Fused launch: blocks [0, gscat) do the bucketed edge scatter (latency-bound,
// ~2% VALU) and blocks [gscat, gscat+Ggemm) do layer-1 GEMM (MFMA-bound) --
// the GEMM fills the pipes the scatter leaves idle.
//
// Scatter: LDS count -> block-local exclusive scan -> one global atomicAdd
// reservation per (block,bucket) -> rank via LDS cursor -> SORT INTO LDS ->
// coalesced run write-out (packed local_dst<<24|src words). Sorting in LDS
// first turns ~55 line-transactions per wave-store into ~6 (runs avg 10.5
// edges with EPB=4096).
__global__ __launch_bounds__(NT) void k_fused(const int* __restrict__ src,
                                              const int* __restrict__ dst,
                                              int* __restrict__ bcursor,
                                              uint32* __restrict__ buck, int nE,
                                              int nbuck, int gscat,
                                              const float* __restrict__ X,
                                              const float* __restrict__ W1,
                                              uint2* __restrict__ Yb, int n) {
  __shared__ FusedSh sm;
  if ((int)blockIdx.x >= gscat) {
    gemm_body<128, 0, 1>(X, W1, Yb, n, ((int)blockIdx.x - gscat) * 64, sm.g.Xh,
                         sm.g.Xl, sm.g.Wt);
    return;
  }
  const int t = threadIdx.x;
  for (int i = t; i < NBUCK_PAD; i += NT) sm.s.cnt[i] = 0;
  __syncthreads();
  const int e0 = blockIdx.x * EPB;
  const int ne = min(EPB, nE - e0);
#pragma unroll
  for (int it = 0; it < ITB; ++it) {
    int e = e0 + it * NT + t;
    if (e < nE) atomicAdd(&sm.s.cnt[dst[e] >> TILE_SH], 1);
  }
  __syncthreads();
  // exclusive scan over 512 padded counters: pair-per-thread + 256-wide scan
  int c0 = sm.s.cnt[2 * t], c1 = sm.s.cnt[2 * t + 1];
  int ps = c0 + c1;
  sm.s.hs[t] = ps;
  __syncthreads();
  for (int o = 1; o < NT; o <<= 1) {
    int x = (t >= o) ? sm.s.hs[t - o] : 0;
    __syncthreads();
    sm.s.hs[t] += x;
    __syncthreads();
  }
  int lb0 = sm.s.hs[t] - ps;  // exclusive base of bucket 2t
  int lb1 = lb0 + c0;         // exclusive base of bucket 2t+1
  sm.s.lcur[2 * t] = lb0;
  sm.s.lcur[2 * t + 1] = lb1;
  {
    int b0 = 2 * t, b1 = 2 * t + 1;
    if (b0 < nbuck) {
      int g0 = c0 ? atomicAdd(&bcursor[b0], c0) : 0;
      sm.s.delta[b0] = (b0 << BSTRIDE_SH) + g0 - lb0;
    }
    if (b1 < nbuck) {
      int g1 = c1 ? atomicAdd(&bcursor[b1], c1) : 0;
      sm.s.delta[b1] = (b1 << BSTRIDE_SH) + g1 - lb1;
    }
  }
  __syncthreads();
#pragma unroll
  for (int it = 0; it < ITB; ++it) {
    int e = e0 + it * NT + t;
    if (e < nE) {
      int d = dst[e];
      int b = d >> TILE_SH;
      int p = atomicAdd(&sm.s.lcur[b], 1);  // p < ne <= EPB by construction
      sm.s.sorted[p] = (uint32)src[e] | ((uint32)(d & (TILE - 1)) << 24);
      sm.s.bid[p] = (unsigned short)b;
    }
  }
  __syncthreads();
  for (int i = t; i < ne; i += NT) {
    int b = sm.s.bid[i];
    int g = sm.s.delta[b] + i;  // = b*BSTRIDE + gbase[b] + local_rank
    if (g < ((b + 1) << BSTRIDE_SH))  // safety clamp (statistically unreachable)
      buck[g] = sm.s.sorted[i];
  }
}

// One block per bucket: LDS hist -> scan -> rowspan{beg,end}/dinv;
// bucket-local srcs SORTED IN LDS then written out contiguously (coalesced).
__global__ __launch_bounds__(NT) void k_bcsr(const uint32* __restrict__ buck,
                                             const int* __restrict__ bcursor,
                                             int2* __restrict__ rowspan,
                                             float* __restrict__ dinv,
                                             int* __restrict__ srcs, int n) {
  __shared__ int hist[TILE];
  __shared__ int hs[NT];
  __shared__ int off[TILE];
  __shared__ uint32 sarr[BSTRIDE];
  const int b = blockIdx.x;
  const int t = threadIdx.x;
  const int W = b * BSTRIDE;
  const int cntb = min(bcursor[b], BSTRIDE);
  const int v0 = b << TILE_SH;
  const int nv = min(TILE, n - v0);
  hist[t] = 0;
  __syncthreads();
  for (int i = t; i < cntb; i += NT) atomicAdd(&hist[buck[W + i] >> 24], 1);
  __syncthreads();
  int h = hist[t];
  hs[t] = h;
  __syncthreads();
  for (int o = 1; o < NT; o <<= 1) {
    int x = (t >= o) ? hs[t - o] : 0;
    __syncthreads();
    hs[t] += x;
    __syncthreads();
  }
  int ex = hs[t] - h;
  off[t] = ex;
  if (t < nv) {
    rowspan[v0 + t] = make_int2(W + ex, W + ex + h);
    dinv[v0 + t] = rsqrtf((float)(h + 1));
  }
  __syncthreads();
  for (int i = t; i < cntb; i += NT) {
    uint32 w = buck[W + i];
    int ld = (int)(w >> 24);
    int p = atomicAdd(&off[ld], 1);  // p < cntb <= BSTRIDE
    sarr[p] = w & 0x00FFFFFFu;
  }
  __syncthreads();
  for (int i = t; i < cntb; i += NT) srcs[W + i] = (int)sarr[i];
}

struct Acc8 {
  float a0, a1, a2, a3, a4, a5, a6, a7;
  __device__ __forceinline__ void madd(uint4 r, float s) {
    a0 = fmaf(bflo(r.x), s, a0); a1 = fmaf(bfhi(r.x), s, a1);
    a2 = fmaf(bflo(r.y), s, a2); a3 = fmaf(bfhi(r.y), s, a3);
    a4 = fmaf(bflo(r.z), s, a4); a5 = fmaf(bfhi(r.z), s, a5);
    a6 = fmaf(bflo(r.w), s, a6); a7 = fmaf(bfhi(r.w), s, a7);
  }
};

// 2 nodes per wave. Per node: 8 lanes x uint4 (16B) cover the 128B bf16 row,
// q in [0,4) edges in flight, unroll x2 => up to 8 row-loads in flight/node.
// Yb rows are now raw X@W (no dinv), so each edge message is scaled by
// dinv[s] here:  out = dv*(sum_s dinv[s]*Yb[s] + dv*Yb[v]) + bias.
template <int RELU, int OUTBF>
__global__ __launch_bounds__(NT) void k_gather(const int2* __restrict__ rowspan,
                                               const int* __restrict__ srcs,
                                               const float* __restrict__ dinv,
                                               const uint4* __restrict__ Xn,
                                               const float* __restrict__ bias,
                                               void* __restrict__ outp, int n) {
  const int gt = blockIdx.x * NT + threadIdx.x;
  const int lane = threadIdx.x & 63;
  const int v = ((gt >> 6) << 1) + (lane >> 5);
  if (v >= n) return;
  const int l5 = lane & 31;
  const int part = l5 & 7;  // uint4 slot in the row
  const int q = l5 >> 3;    // edge in flight
  const int2 rs = rowspan[v];
  const int beg = rs.x, end = rs.y;
  const float dv = dinv[v];
  Acc8 A = {0.f, 0.f, 0.f, 0.f, 0.f, 0.f, 0.f, 0.f};
  int j = beg + q;
  for (; j + 4 < end; j += 8) {
    int s0 = srcs[j];
    int s1 = srcs[j + 4];
    float ds0 = dinv[s0];
    float ds1 = dinv[s1];
    uint4 r0 = Xn[(size_t)s0 * 8 + part];
    uint4 r1 = Xn[(size_t)s1 * 8 + part];
    A.madd(r0, ds0);
    A.madd(r1, ds1);
  }
  if (j < end) {
    int s = srcs[j];
    A.madd(Xn[(size_t)s * 8 + part], dinv[s]);
  }
#pragma unroll
  for (int m = 8; m <= 16; m <<= 1) {
    A.a0 += __shfl_xor(A.a0, m);
    A.a1 += __shfl_xor(A.a1, m);
    A.a2 += __shfl_xor(A.a2, m);
    A.a3 += __shfl_xor(A.a3, m);
    A.a4 += __shfl_xor(A.a4, m);
    A.a5 += __shfl_xor(A.a5, m);
    A.a6 += __shfl_xor(A.a6, m);
    A.a7 += __shfl_xor(A.a7, m);
  }
  if (q == 0) {
    uint4 wv = Xn[(size_t)v * 8 + part];
    const float4* b4 = (const float4*)bias;
    float4 b0 = b4[part * 2], b1 = b4[part * 2 + 1];
    float r0 = dv * (A.a0 + dv * bflo(wv.x)) + b0.x;
    float r1 = dv * (A.a1 + dv * bfhi(wv.x)) + b0.y;
    float r2 = dv * (A.a2 + dv * bflo(wv.y)) + b0.z;
    float r3 = dv * (A.a3 + dv * bfhi(wv.y)) + b0.w;
    float r4 = dv * (A.a4 + dv * bflo(wv.z)) + b1.x;
    float r5 = dv * (A.a5 + dv * bfhi(wv.z)) + b1.y;
    float r6 = dv * (A.a6 + dv * bflo(wv.w)) + b1.z;
    float r7 = dv * (A.a7 + dv * bfhi(wv.w)) + b1.w;
    if (RELU) {
      r0 = fmaxf(r0, 0.f); r1 = fmaxf(r1, 0.f); r2 = fmaxf(r2, 0.f); r3 = fmaxf(r3, 0.f);
      r4 = fmaxf(r4, 0.f); r5 = fmaxf(r5, 0.f); r6 = fmaxf(r6, 0.f); r7 = fmaxf(r7, 0.f);
    }
    if (OUTBF) {
      uint4 u;
      u.x = (uint32)f2bf(r0) | ((uint32)f2bf(r1) << 16);
      u.y = (uint32)f2bf(r2) | ((uint32)f2bf(r3) << 16);
      u.z = (uint32)f2bf(r4) | ((uint32)f2bf(r5) << 16);
      u.w = (uint32)f2bf(r6) | ((uint32)f2bf(r7) << 16);
      ((uint4*)outp)[(size_t)v * 8 + part] = u;
    } else {
      float4* o4 = (float4*)outp;
      o4[(size_t)v * 16 + part * 2] = make_float4(r0, r1, r2, r3);
      o4[(size_t)v * 16 + part * 2 + 1] = make_float4(r4, r5, r6, r7);
    }
  }
}

// Layer-2 standalone GEMM (H bf16 @ W2), no dinv.
__global__ __launch_bounds__(NT) void k_gemm2(const void* __restrict__ Xp,
                                              const float* __restrict__ W,
                                              uint2* __restrict__ Yb, int n) {
  __shared__ unsigned short Xh[64 * 72];
  __shared__ unsigned short Wt[64 * 72];
  gemm_body<64, 1, 0>(Xp, W, Yb, n, blockIdx.x * 64, Xh, Xh /*unused*/, Wt);
}

extern "C" void kernel_launch(void* const* d_in, const int* in_sizes, int n_in,
                              void* d_out, int out_size, void* d_ws, size_t ws_size,
                              hipStream_t stream) {
  // setup_inputs order: V, E, X, W1, b1, W2, b2
  const int* E = (const int*)d_in[1];
  const float* X = (const float*)d_in[2];
  const float* W1 = (const float*)d_in[3];
  const float* b1 = (const float*)d_in[4];
  const float* W2 = (const float*)d_in[5];
  const float* b2 = (const float*)d_in[6];
  float* out = (float*)d_out;

  const int n = in_sizes[2] / 128;  // 100000
  const int nE = in_sizes[1] / 2;   // 1600000
  const int* src = E;
  const int* dst = E + nE;
  const int nbuck = cdiv(n, TILE);  // 391

  char* ws = (char*)d_ws;
  size_t off = 0;
  auto alloc = [&](size_t bytes) {
    size_t o = off;
    off = (off + bytes + 255) & ~(size_t)255;
    return (void*)(ws + o);
  };
  int2* rowspan = (int2*)alloc((size_t)n * 8);
  float* dinv = (float*)alloc((size_t)n * 4);
  int* bcursor = (int*)alloc((size_t)nbuck * 4);
  uint32* buck = (uint32*)alloc((size_t)nbuck * BSTRIDE * 4);
  int* srcs = (int*)alloc((size_t)nbuck * BSTRIDE * 4);
  uint2* Xn = (uint2*)alloc((size_t)n * 64 * 2);  // bf16 rows, 128 B each
  uint2* H = (uint2*)alloc((size_t)n * 64 * 2);   // bf16 rows, 128 B each

  const int gscat = cdiv(nE, EPB);       // 391
  const int ggemm = cdiv(n, 64);         // 1563
  const int gthreads_blocks = cdiv((long long)n * 32, NT);

  hipMemsetAsync(bcursor, 0, (size_t)nbuck * 4, stream);

  // --- CSR build (scatter) + layer-1 GEMM, fused into one launch ---
  k_fused<<<gscat + ggemm, NT, 0, stream>>>(src, dst, bcursor, buck, nE, nbuck,
                                            gscat, X, W1, Xn, n);
  k_bcsr<<<nbuck, NT, 0, stream>>>(buck, bcursor, rowspan, dinv, srcs, n);

  // --- layer 1 aggregate ---
  k_gather<1, 1><<<gthreads_blocks, NT, 0, stream>>>(rowspan, srcs, dinv,
                                                     (const uint4*)Xn, b1, H, n);

  // --- layer 2 ---
  k_gemm2<<<cdiv(n, 64), NT, 0, stream>>>(H, W2, Xn, n);
  k_gather<0, 0><<<gthreads_blocks, NT, 0, stream>>>(rowspan, srcs, dinv,
                                                     (const uint4*)Xn, b2, out, n);
}

// Round 2
// 233.071 us; speedup vs baseline: 1.1249x; 1.0509x over previous
//
#include <hip/hip_runtime.h>

#define NT 256
#define TILE 256      // nodes per bucket
#define TILE_SH 8
#define BSTRIDE 8192  // padded edge slots per bucket (mean 4096, sigma 64)
#define BSTRIDE_SH 13
#define EPB 4096      // edges per block in bucket scatter pass
#define ITB 16        // EPB / NT
#define NBUCK_PAD 512

static inline int cdiv(long long a, long long b) { return (int)((a + b - 1) / b); }

typedef unsigned int uint32;
typedef unsigned short ushort16;
typedef short bf16x8 __attribute__((ext_vector_type(8)));
typedef float f32x4 __attribute__((ext_vector_type(4)));

__device__ __forceinline__ ushort16 f2bf(float f) {
  uint32 u = __float_as_uint(f);
  u = (u + 0x7FFF + ((u >> 16) & 1)) >> 16;  // round-to-nearest-even
  return (ushort16)u;
}
__device__ __forceinline__ float bflo(uint32 w) { return __uint_as_float(w << 16); }
__device__ __forceinline__ float bfhi(uint32 w) { return __uint_as_float(w & 0xFFFF0000u); }
__device__ __forceinline__ float bf2f(ushort16 h) { return __uint_as_float(((uint32)h) << 16); }

// ---- MFMA GEMM, X direct-to-register (no X LDS staging) ----
// Yb[v,0:64] = bf16(X[v,0:K] @ W[K,64]); W staged once per block in LDS (bf16,
// transposed Wt[n][k]); each lane loads its OWN B-fragment (8 contiguous elems
// of its row) straight from global: a wave's 64 lanes cover 16 rows x 128 B
// contiguous -> full line utilization, no staging barrier, no Xh/Xl LDS.
// SPLIT: fp32 X -> hi+lo bf16 in registers, 2 chained MFMAs.
// BFIN: X rows already bf16-packed (exact A operand).
template <int K>
__device__ __forceinline__ void stage_W(const float* __restrict__ W,
                                        unsigned short* __restrict__ Wt) {
  constexpr int STR = K + 8;
  for (int i = threadIdx.x; i < K * 64; i += NT) {
    int k = i >> 6, nn = i & 63;
    Wt[nn * STR + k] = f2bf(W[i]);
  }
}

template <int K, int BFIN, int SPLIT>
__device__ __forceinline__ void gemm_tile(const void* __restrict__ Xp,
                                          const unsigned short* __restrict__ Wt,
                                          uint2* __restrict__ Yb, int n, int base) {
  constexpr int STR = K + 8;
  const int tid = threadIdx.x;
  const int w = tid >> 6;
  const int lane = tid & 63;
  const int r = lane & 15;
  const int quad = lane >> 4;
  const int rloc = w * 16 + r;
  const int v = base + rloc;

  f32x4 acc[4];
#pragma unroll
  for (int i = 0; i < 4; ++i) acc[i] = (f32x4)(0.f);

  if (BFIN) {
    const uint4* X4 = (const uint4*)Xp;  // K/8 uint4 per row
    bf16x8 xf[K / 32];
#pragma unroll
    for (int ks = 0; ks < K / 32; ++ks) {
      uint4 u = make_uint4(0u, 0u, 0u, 0u);
      if (v < n) u = X4[(size_t)v * (K / 8) + ks * 4 + quad];
      xf[ks] = *(const bf16x8*)&u;
    }
#pragma unroll
    for (int ks = 0; ks < K / 32; ++ks) {
      const int koff = ks * 32 + quad * 8;
#pragma unroll
      for (int nt = 0; nt < 4; ++nt) {
        bf16x8 wf = *(const bf16x8*)&Wt[(nt * 16 + r) * STR + koff];
        acc[nt] = __builtin_amdgcn_mfma_f32_16x16x32_bf16(wf, xf[ks], acc[nt], 0, 0, 0);
      }
    }
  } else {
    const float4* X4 = (const float4*)Xp;  // K/4 float4 per row
    float4 a[K / 32][2];
#pragma unroll
    for (int ks = 0; ks < K / 32; ++ks) {
      a[ks][0] = make_float4(0.f, 0.f, 0.f, 0.f);
      a[ks][1] = make_float4(0.f, 0.f, 0.f, 0.f);
      if (v < n) {
        a[ks][0] = X4[(size_t)v * (K / 4) + ks * 8 + quad * 2];
        a[ks][1] = X4[(size_t)v * (K / 4) + ks * 8 + quad * 2 + 1];
      }
    }
#pragma unroll
    for (int ks = 0; ks < K / 32; ++ks) {
      float f[8] = {a[ks][0].x, a[ks][0].y, a[ks][0].z, a[ks][0].w,
                    a[ks][1].x, a[ks][1].y, a[ks][1].z, a[ks][1].w};
      bf16x8 xh, xl;
#pragma unroll
      for (int j = 0; j < 8; ++j) {
        ushort16 h = f2bf(f[j]);
        xh[j] = (short)h;
        if (SPLIT) xl[j] = (short)f2bf(f[j] - bf2f(h));
      }
      const int koff = ks * 32 + quad * 8;
#pragma unroll
      for (int nt = 0; nt < 4; ++nt) {
        bf16x8 wf = *(const bf16x8*)&Wt[(nt * 16 + r) * STR + koff];
        if (SPLIT)
          acc[nt] = __builtin_amdgcn_mfma_f32_16x16x32_bf16(wf, xl, acc[nt], 0, 0, 0);
        acc[nt] = __builtin_amdgcn_mfma_f32_16x16x32_bf16(wf, xh, acc[nt], 0, 0, 0);
      }
    }
  }

  if (v < n) {
#pragma unroll
    for (int nt = 0; nt < 4; ++nt) {
      // reg i holds out-dim n = nt*16 + quad*4 + i for node v
      uint2 u;
      u.x = (uint32)f2bf(acc[nt][0]) | ((uint32)f2bf(acc[nt][1]) << 16);
      u.y = (uint32)f2bf(acc[nt][2]) | ((uint32)f2bf(acc[nt][3]) << 16);
      Yb[(size_t)v * 16 + nt * 4 + quad] = u;
    }
  }
}

struct ScatSh {
  int cnt[NBUCK_PAD];
  int lcur[NBUCK_PAD];
  int delta[NBUCK_PAD];
  int hs[NT];
  uint32 sorted[EPB];
  unsigned short bid[EPB];
};
union FusedSh {
  unsigned short wt[64 * 136];  // 17.4 KB
  ScatSh s;                     // 31.7 KB  -> union 31.7 KB, 4+ blocks/CU
};

// Fused launch: blocks [0, gscat) do the bucketed edge scatter (latency-bound)
// and blocks [gscat, gscat+ggemm) grid-stride over layer-1 GEMM tiles.
// grid = 1024 total = full residency at 4 blocks/CU -> true overlap.
__global__ __launch_bounds__(NT, 4) void k_fused(
    const int* __restrict__ src, const int* __restrict__ dst,
    int* __restrict__ bcursor, uint32* __restrict__ buck, int nE, int nbuck,
    int gscat, int ggemm, int ntile, const float* __restrict__ X,
    const float* __restrict__ W1, uint2* __restrict__ Yb, int n) {
  __shared__ FusedSh sm;
  if ((int)blockIdx.x >= gscat) {
    stage_W<128>(W1, sm.wt);
    __syncthreads();
    for (int tile = (int)blockIdx.x - gscat; tile < ntile; tile += ggemm)
      gemm_tile<128, 0, 1>(X, sm.wt, Yb, n, tile * 64);
    return;
  }
  const int t = threadIdx.x;
  for (int i = t; i < NBUCK_PAD; i += NT) sm.s.cnt[i] = 0;
  __syncthreads();
  const int e0 = blockIdx.x * EPB;
  const int ne = min(EPB, nE - e0);
  int dreg[ITB];
#pragma unroll
  for (int it = 0; it < ITB; ++it) {
    int e = e0 + it * NT + t;
    dreg[it] = (e < nE) ? dst[e] : -1;
    if (dreg[it] >= 0) atomicAdd(&sm.s.cnt[dreg[it] >> TILE_SH], 1);
  }
  __syncthreads();
  // exclusive scan over 512 padded counters: pair-per-thread + 256-wide scan
  int c0 = sm.s.cnt[2 * t], c1 = sm.s.cnt[2 * t + 1];
  int ps = c0 + c1;
  sm.s.hs[t] = ps;
  __syncthreads();
  for (int o = 1; o < NT; o <<= 1) {
    int x = (t >= o) ? sm.s.hs[t - o] : 0;
    __syncthreads();
    sm.s.hs[t] += x;
    __syncthreads();
  }
  int lb0 = sm.s.hs[t] - ps;  // exclusive base of bucket 2t
  int lb1 = lb0 + c0;         // exclusive base of bucket 2t+1
  sm.s.lcur[2 * t] = lb0;
  sm.s.lcur[2 * t + 1] = lb1;
  {
    int b0 = 2 * t, b1 = 2 * t + 1;
    if (b0 < nbuck) {
      int g0 = c0 ? atomicAdd(&bcursor[b0], c0) : 0;
      sm.s.delta[b0] = (b0 << BSTRIDE_SH) + g0 - lb0;
    }
    if (b1 < nbuck) {
      int g1 = c1 ? atomicAdd(&bcursor[b1], c1) : 0;
      sm.s.delta[b1] = (b1 << BSTRIDE_SH) + g1 - lb1;
    }
  }
  __syncthreads();
#pragma unroll
  for (int it = 0; it < ITB; ++it) {
    int e = e0 + it * NT + t;
    if (dreg[it] >= 0) {
      int d = dreg[it];
      int b = d >> TILE_SH;
      int p = atomicAdd(&sm.s.lcur[b], 1);  // p < ne <= EPB by construction
      sm.s.sorted[p] = (uint32)src[e] | ((uint32)(d & (TILE - 1)) << 24);
      sm.s.bid[p] = (unsigned short)b;
    }
  }
  __syncthreads();
  for (int i = t; i < ne; i += NT) {
    int b = sm.s.bid[i];
    int g = sm.s.delta[b] + i;  // = b*BSTRIDE + gbase[b] + local_rank
    if (g < ((b + 1) << BSTRIDE_SH))  // safety clamp (statistically unreachable)
      buck[g] = sm.s.sorted[i];
  }
}

// One block per bucket: LDS hist -> scan -> rowspan{beg,end}/dinv;
// bucket-local srcs SORTED IN LDS then written out contiguously (coalesced).
__global__ __launch_bounds__(NT) void k_bcsr(const uint32* __restrict__ buck,
                                             const int* __restrict__ bcursor,
                                             int2* __restrict__ rowspan,
                                             float* __restrict__ dinv,
                                             int* __restrict__ srcs, int n) {
  __shared__ int hist[TILE];
  __shared__ int hs[NT];
  __shared__ int off[TILE];
  __shared__ uint32 sarr[BSTRIDE];
  const int b = blockIdx.x;
  const int t = threadIdx.x;
  const int W = b * BSTRIDE;
  const int cntb = min(bcursor[b], BSTRIDE);
  const int v0 = b << TILE_SH;
  const int nv = min(TILE, n - v0);
  hist[t] = 0;
  __syncthreads();
  for (int i = t; i < cntb; i += NT) atomicAdd(&hist[buck[W + i] >> 24], 1);
  __syncthreads();
  int h = hist[t];
  hs[t] = h;
  __syncthreads();
  for (int o = 1; o < NT; o <<= 1) {
    int x = (t >= o) ? hs[t - o] : 0;
    __syncthreads();
    hs[t] += x;
    __syncthreads();
  }
  int ex = hs[t] - h;
  off[t] = ex;
  if (t < nv) {
    rowspan[v0 + t] = make_int2(W + ex, W + ex + h);
    dinv[v0 + t] = rsqrtf((float)(h + 1));
  }
  __syncthreads();
  for (int i = t; i < cntb; i += NT) {
    uint32 w = buck[W + i];
    int ld = (int)(w >> 24);
    int p = atomicAdd(&off[ld], 1);  // p < cntb <= BSTRIDE
    sarr[p] = w & 0x00FFFFFFu;
  }
  __syncthreads();
  for (int i = t; i < cntb; i += NT) srcs[W + i] = (int)sarr[i];
}

struct Acc8 {
  float a0, a1, a2, a3, a4, a5, a6, a7;
  __device__ __forceinline__ void madd(uint4 r, float s) {
    a0 = fmaf(bflo(r.x), s, a0); a1 = fmaf(bfhi(r.x), s, a1);
    a2 = fmaf(bflo(r.y), s, a2); a3 = fmaf(bfhi(r.y), s, a3);
    a4 = fmaf(bflo(r.z), s, a4); a5 = fmaf(bfhi(r.z), s, a5);
    a6 = fmaf(bflo(r.w), s, a6); a7 = fmaf(bfhi(r.w), s, a7);
  }
};

// 2 nodes per wave. Per node: 8 lanes x uint4 (16B) cover the 128B bf16 row,
// q in [0,4) edges in flight, unroll x2 => up to 8 row-loads in flight/node.
// Yb rows are raw X@W (no dinv), so each edge message is scaled by dinv[s]:
// out = dv*(sum_s dinv[s]*Yb[s] + dv*Yb[v]) + bias.
template <int RELU, int OUTBF>
__global__ __launch_bounds__(NT) void k_gather(const int2* __restrict__ rowspan,
                                               const int* __restrict__ srcs,
                                               const float* __restrict__ dinv,
                                               const uint4* __restrict__ Xn,
                                               const float* __restrict__ bias,
                                               void* __restrict__ outp, int n) {
  const int gt = blockIdx.x * NT + threadIdx.x;
  const int lane = threadIdx.x & 63;
  const int v = ((gt >> 6) << 1) + (lane >> 5);
  if (v >= n) return;
  const int l5 = lane & 31;
  const int part = l5 & 7;  // uint4 slot in the row
  const int q = l5 >> 3;    // edge in flight
  const int2 rs = rowspan[v];
  const int beg = rs.x, end = rs.y;
  const float dv = dinv[v];
  Acc8 A = {0.f, 0.f, 0.f, 0.f, 0.f, 0.f, 0.f, 0.f};
  int j = beg + q;
  for (; j + 4 < end; j += 8) {
    int s0 = srcs[j];
    int s1 = srcs[j + 4];
    float ds0 = dinv[s0];
    float ds1 = dinv[s1];
    uint4 r0 = Xn[(size_t)s0 * 8 + part];
    uint4 r1 = Xn[(size_t)s1 * 8 + part];
    A.madd(r0, ds0);
    A.madd(r1, ds1);
  }
  if (j < end) {
    int s = srcs[j];
    A.madd(Xn[(size_t)s * 8 + part], dinv[s]);
  }
#pragma unroll
  for (int m = 8; m <= 16; m <<= 1) {
    A.a0 += __shfl_xor(A.a0, m);
    A.a1 += __shfl_xor(A.a1, m);
    A.a2 += __shfl_xor(A.a2, m);
    A.a3 += __shfl_xor(A.a3, m);
    A.a4 += __shfl_xor(A.a4, m);
    A.a5 += __shfl_xor(A.a5, m);
    A.a6 += __shfl_xor(A.a6, m);
    A.a7 += __shfl_xor(A.a7, m);
  }
  if (q == 0) {
    uint4 wv = Xn[(size_t)v * 8 + part];
    const float4* b4 = (const float4*)bias;
    float4 b0 = b4[part * 2], b1 = b4[part * 2 + 1];
    float r0 = dv * (A.a0 + dv * bflo(wv.x)) + b0.x;
    float r1 = dv * (A.a1 + dv * bfhi(wv.x)) + b0.y;
    float r2 = dv * (A.a2 + dv * bflo(wv.y)) + b0.z;
    float r3 = dv * (A.a3 + dv * bfhi(wv.y)) + b0.w;
    float r4 = dv * (A.a4 + dv * bflo(wv.z)) + b1.x;
    float r5 = dv * (A.a5 + dv * bfhi(wv.z)) + b1.y;
    float r6 = dv * (A.a6 + dv * bflo(wv.w)) + b1.z;
    float r7 = dv * (A.a7 + dv * bfhi(wv.w)) + b1.w;
    if (RELU) {
      r0 = fmaxf(r0, 0.f); r1 = fmaxf(r1, 0.f); r2 = fmaxf(r2, 0.f); r3 = fmaxf(r3, 0.f);
      r4 = fmaxf(r4, 0.f); r5 = fmaxf(r5, 0.f); r6 = fmaxf(r6, 0.f); r7 = fmaxf(r7, 0.f);
    }
    if (OUTBF) {
      uint4 u;
      u.x = (uint32)f2bf(r0) | ((uint32)f2bf(r1) << 16);
      u.y = (uint32)f2bf(r2) | ((uint32)f2bf(r3) << 16);
      u.z = (uint32)f2bf(r4) | ((uint32)f2bf(r5) << 16);
      u.w = (uint32)f2bf(r6) | ((uint32)f2bf(r7) << 16);
      ((uint4*)outp)[(size_t)v * 8 + part] = u;
    } else {
      float4* o4 = (float4*)outp;
      o4[(size_t)v * 16 + part * 2] = make_float4(r0, r1, r2, r3);
      o4[(size_t)v * 16 + part * 2 + 1] = make_float4(r4, r5, r6, r7);
    }
  }
}

// Layer-2 GEMM (H bf16 @ W2): Wt-only LDS (9.2 KB), direct fragment loads,
// grid-stride tiles.
__global__ __launch_bounds__(NT, 4) void k_gemm2(const void* __restrict__ Xp,
                                                 const float* __restrict__ W,
                                                 uint2* __restrict__ Yb, int n,
                                                 int gg, int ntile) {
  __shared__ unsigned short Wt[64 * 72];
  stage_W<64>(W, Wt);
  __syncthreads();
  for (int tile = (int)blockIdx.x; tile < ntile; tile += gg)
    gemm_tile<64, 1, 0>(Xp, Wt, Yb, n, tile * 64);
}

extern "C" void kernel_launch(void* const* d_in, const int* in_sizes, int n_in,
                              void* d_out, int out_size, void* d_ws, size_t ws_size,
                              hipStream_t stream) {
  // setup_inputs order: V, E, X, W1, b1, W2, b2
  const int* E = (const int*)d_in[1];
  const float* X = (const float*)d_in[2];
  const float* W1 = (const float*)d_in[3];
  const float* b1 = (const float*)d_in[4];
  const float* W2 = (const float*)d_in[5];
  const float* b2 = (const float*)d_in[6];
  float* out = (float*)d_out;

  const int n = in_sizes[2] / 128;  // 100000
  const int nE = in_sizes[1] / 2;   // 1600000
  const int* src = E;
  const int* dst = E + nE;
  const int nbuck = cdiv(n, TILE);  // 391

  char* ws = (char*)d_ws;
  size_t off = 0;
  auto alloc = [&](size_t bytes) {
    size_t o = off;
    off = (off + bytes + 255) & ~(size_t)255;
    return (void*)(ws + o);
  };
  int2* rowspan = (int2*)alloc((size_t)n * 8);
  float* dinv = (float*)alloc((size_t)n * 4);
  int* bcursor = (int*)alloc((size_t)nbuck * 4);
  uint32* buck = (uint32*)alloc((size_t)nbuck * BSTRIDE * 4);
  int* srcs = (int*)alloc((size_t)nbuck * BSTRIDE * 4);
  uint2* Xn = (uint2*)alloc((size_t)n * 64 * 2);  // bf16 rows, 128 B each
  uint2* H = (uint2*)alloc((size_t)n * 64 * 2);   // bf16 rows, 128 B each

  const int gscat = cdiv(nE, EPB);  // 391
  const int ntile = cdiv(n, 64);    // 1563
  const int ggemm = 1024 - gscat;   // 633: grid = 1024 = 4 blocks/CU residency
  const int gthreads_blocks = cdiv((long long)n * 32, NT);

  hipMemsetAsync(bcursor, 0, (size_t)nbuck * 4, stream);

  // --- CSR build (scatter) + layer-1 GEMM, fused into one fully-resident launch ---
  k_fused<<<gscat + ggemm, NT, 0, stream>>>(src, dst, bcursor, buck, nE, nbuck,
                                            gscat, ggemm, ntile, X, W1, Xn, n);
  k_bcsr<<<nbuck, NT, 0, stream>>>(buck, bcursor, rowspan, dinv, srcs, n);

  // --- layer 1 aggregate ---
  k_gather<1, 1><<<gthreads_blocks, NT, 0, stream>>>(rowspan, srcs, dinv,
                                                     (const uint4*)Xn, b1, H, n);

  // --- layer 2 ---
  k_gemm2<<<1024, NT, 0, stream>>>(H, W2, Xn, n, 1024, ntile);
  k_gather<0, 0><<<gthreads_blocks, NT, 0, stream>>>(rowspan, srcs, dinv,
                                                     (const uint4*)Xn, b2, out, n);
}